// Round 12
// baseline (608.732 us; speedup 1.0000x reference)
//
#include <hip/hip_runtime.h>

typedef _Float16 f16;
typedef _Float16 half8 __attribute__((ext_vector_type(8)));
typedef float floatx4 __attribute__((ext_vector_type(4)));

#define L_TOT   3072
#define L_NZ    2048
#define DIM_C   2048
#define NH      16
#define HD      128

// ---------------------------------------------------------------- helpers
__device__ __forceinline__ void gl_lds16(const f16* g, f16* l) {
    __builtin_amdgcn_global_load_lds((__attribute__((address_space(1))) void*)g,
                                     (__attribute__((address_space(3))) void*)l,
                                     16, 0, 0);
}

__global__ void sentinel_kernel(float* out) { out[0] = 1.0e6f; }

// ---------------------------------------------------------------- fused cast: joint = [noise;cond] f32 -> f16
__global__ __launch_bounds__(256)
void cast_joint(const float* __restrict__ noise, const float* __restrict__ cond,
                f16* __restrict__ out) {
    int i = (blockIdx.x * 256 + threadIdx.x) * 4;
    const float* src; int off;
    if (i < 2048 * 2048) { src = noise; off = i; }
    else                 { src = cond;  off = i - 2048 * 2048; }
    float4 v = *(const float4*)(src + off);
    out[i+0] = (f16)v.x; out[i+1] = (f16)v.y;
    out[i+2] = (f16)v.z; out[i+3] = (f16)v.w;
}

// ---------------------------------------------------------------- batched transpose(+cast): out[z][c][r] = in_z[r][c]
__global__ __launch_bounds__(256)
void transpose_cast4(const float* __restrict__ s0, const float* __restrict__ s1,
                     const float* __restrict__ s2, const float* __restrict__ s3,
                     f16* __restrict__ dstBase, int R, int C, long long outBatch) {
    const float* in = (blockIdx.z == 0) ? s0 : (blockIdx.z == 1) ? s1 : (blockIdx.z == 2) ? s2 : s3;
    f16* out = dstBase + (long long)blockIdx.z * outBatch;
    __shared__ f16 tile[32][33];
    int x = threadIdx.x & 31, y0 = threadIdx.x >> 5;
    int r0 = blockIdx.y * 32, c0 = blockIdx.x * 32;
#pragma unroll
    for (int i = 0; i < 4; ++i) {
        int y = y0 + i * 8;
        tile[y][x] = (f16)in[(size_t)(r0 + y) * C + (c0 + x)];
    }
    __syncthreads();
#pragma unroll
    for (int i = 0; i < 4; ++i) {
        int y = y0 + i * 8;
        out[(size_t)(c0 + y) * R + (r0 + x)] = tile[x][y];
    }
}

// ---------------------------------------------------------------- GEMM v2 (template): C = A * BT^T
// 128x128 tile, BK=64, XOR-swizzled LDS, double-buffered counted vmcnt(8).
// MODE 0: plain. MODE 2: lora-up merged (A += chunk*128, per-chunk C base).
template<int WRITE_HALF, int ACCUM, int ADD_BIAS, int MODE>
__global__ __launch_bounds__(256, 2)
void gemm_tn(const f16* __restrict__ A, const f16* __restrict__ BT,
             void* __restrict__ Cv,
             const float* __restrict__ bias0,
             int M, int N, int K, int lda, int ldb, int ldc) {
    __shared__ __align__(16) f16 lds[2][2][128 * 64];
    const int tid  = threadIdx.x;
    const int lane = tid & 63, wave = tid >> 6;
    const int m0 = blockIdx.y * 128, n0 = blockIdx.x * 128;
    const int wr = wave >> 1, wc = wave & 1;
    floatx4 acc[4][4] = {};

    if (MODE == 2) A += (size_t)(n0 >> 11) * 128;

    const int r0i = tid >> 3;
    const int gch = (tid & 7) ^ (r0i & 7);
    const f16* gA0 = A  + (size_t)(m0 + r0i) * lda + gch * 8;
    const f16* gB0 = BT + (size_t)(n0 + r0i) * ldb + gch * 8;
    const int ldsW = wave * 512;

    auto stage = [&](int buf, int k0) {
#pragma unroll
        for (int is = 0; is < 4; ++is)
            gl_lds16(gA0 + k0 + (size_t)is * 32 * lda, &lds[buf][0][0] + is * 2048 + ldsW);
#pragma unroll
        for (int is = 0; is < 4; ++is)
            gl_lds16(gB0 + k0 + (size_t)is * 32 * ldb, &lds[buf][1][0] + is * 2048 + ldsW);
    };

    const int rl = lane & 15, cq = lane >> 4;

    const int nIter = K >> 6;
    stage(0, 0);
    int cur = 0;
    for (int t = 0; t < nIter; ++t) {
        const int k0n = (t + 1 < nIter) ? (t + 1) * 64 : 0;
        stage(cur ^ 1, k0n);
        asm volatile("s_waitcnt vmcnt(8)" ::: "memory");
        __builtin_amdgcn_s_barrier();
        __builtin_amdgcn_sched_barrier(0);
#pragma unroll
        for (int kh = 0; kh < 2; ++kh) {
            half8 af[4], bf[4];
#pragma unroll
            for (int m = 0; m < 4; ++m) {
                int row = wr * 64 + m * 16 + rl;
                int pos = (kh * 4 + cq) ^ (row & 7);
                af[m] = *(const half8*)(&lds[cur][0][row * 64 + pos * 8]);
            }
#pragma unroll
            for (int n = 0; n < 4; ++n) {
                int row = wc * 64 + n * 16 + rl;
                int pos = (kh * 4 + cq) ^ (row & 7);
                bf[n] = *(const half8*)(&lds[cur][1][row * 64 + pos * 8]);
            }
#pragma unroll
            for (int m = 0; m < 4; ++m)
#pragma unroll
                for (int n = 0; n < 4; ++n)
                    acc[m][n] = __builtin_amdgcn_mfma_f32_16x16x32_f16(af[m], bf[n], acc[m][n], 0, 0, 0);
        }
        __builtin_amdgcn_s_barrier();
        __builtin_amdgcn_sched_barrier(0);
        cur ^= 1;
    }

    const int rq = lane >> 4;
    size_t cbase = 0;
    if (MODE == 2) cbase = (size_t)(n0 >> 11) * ((size_t)L_TOT * DIM_C);
#pragma unroll
    for (int m = 0; m < 4; ++m) {
        int row = m0 + wr * 64 + m * 16 + rq * 4;
#pragma unroll
        for (int n = 0; n < 4; ++n) {
            int col = n0 + wc * 64 + n * 16 + rl;
            int ccol = (MODE == 2) ? (col & 2047) : col;
            float badd = ADD_BIAS ? bias0[ccol] : 0.0f;
#pragma unroll
            for (int j = 0; j < 4; ++j) {
                float v = acc[m][n][j] + badd;
                size_t idx = cbase + (size_t)(row + j) * ldc + ccol;
                if (WRITE_HALF) {
                    f16* C = (f16*)Cv;
                    if (ACCUM) v += (float)C[idx];
                    C[idx] = (f16)v;
                } else {
                    float* C = (float*)Cv;
                    if (ACCUM) v += C[idx];
                    C[idx] = v;
                }
            }
        }
    }
}

// ---------------------------------------------------------------- dual-job GEMM (runtime params; hot loop identical)
__global__ __launch_bounds__(256, 2)
void gemm_pair(int nb0, int nbx0,
               const f16* __restrict__ A0, const f16* __restrict__ BT0, void* C0,
               const float* __restrict__ b00, const float* __restrict__ b01, const float* __restrict__ b02,
               int lda0, int ldb0, int ldc0, int wh0, int ab0, int mode0,
               int nbx1,
               const f16* __restrict__ A1, const f16* __restrict__ BT1, void* C1,
               int lda1, int ldb1, int ldc1, int wh1,
               int K) {
    __shared__ __align__(16) f16 lds[2][2][128 * 64];
    const int tid  = threadIdx.x;
    const int lane = tid & 63, wave = tid >> 6;
    const int bid = blockIdx.x;
    const bool j0 = (bid < nb0);
    const int lb  = j0 ? bid : (bid - nb0);
    const int nbx = j0 ? nbx0 : nbx1;
    const int bx = lb % nbx, by = lb / nbx;
    const int m0 = by * 128, n0 = bx * 128;
    const f16* A  = j0 ? A0  : A1;
    const f16* BT = j0 ? BT0 : BT1;
    const int lda = j0 ? lda0 : lda1, ldb = j0 ? ldb0 : ldb1, ldc = j0 ? ldc0 : ldc1;
    const int wr = wave >> 1, wc = wave & 1;
    floatx4 acc[4][4] = {};

    const int r0i = tid >> 3;
    const int gch = (tid & 7) ^ (r0i & 7);
    const f16* gA0 = A  + (size_t)(m0 + r0i) * lda + gch * 8;
    const f16* gB0 = BT + (size_t)(n0 + r0i) * ldb + gch * 8;
    const int ldsW = wave * 512;

    auto stage = [&](int buf, int k0) {
#pragma unroll
        for (int is = 0; is < 4; ++is)
            gl_lds16(gA0 + k0 + (size_t)is * 32 * lda, &lds[buf][0][0] + is * 2048 + ldsW);
#pragma unroll
        for (int is = 0; is < 4; ++is)
            gl_lds16(gB0 + k0 + (size_t)is * 32 * ldb, &lds[buf][1][0] + is * 2048 + ldsW);
    };

    const int rl = lane & 15, cq = lane >> 4;
    const int nIter = K >> 6;
    stage(0, 0);
    int cur = 0;
    for (int t = 0; t < nIter; ++t) {
        const int k0n = (t + 1 < nIter) ? (t + 1) * 64 : 0;
        stage(cur ^ 1, k0n);
        asm volatile("s_waitcnt vmcnt(8)" ::: "memory");
        __builtin_amdgcn_s_barrier();
        __builtin_amdgcn_sched_barrier(0);
#pragma unroll
        for (int kh = 0; kh < 2; ++kh) {
            half8 af[4], bf[4];
#pragma unroll
            for (int m = 0; m < 4; ++m) {
                int row = wr * 64 + m * 16 + rl;
                int pos = (kh * 4 + cq) ^ (row & 7);
                af[m] = *(const half8*)(&lds[cur][0][row * 64 + pos * 8]);
            }
#pragma unroll
            for (int n = 0; n < 4; ++n) {
                int row = wc * 64 + n * 16 + rl;
                int pos = (kh * 4 + cq) ^ (row & 7);
                bf[n] = *(const half8*)(&lds[cur][1][row * 64 + pos * 8]);
            }
#pragma unroll
            for (int m = 0; m < 4; ++m)
#pragma unroll
                for (int n = 0; n < 4; ++n)
                    acc[m][n] = __builtin_amdgcn_mfma_f32_16x16x32_f16(af[m], bf[n], acc[m][n], 0, 0, 0);
        }
        __builtin_amdgcn_s_barrier();
        __builtin_amdgcn_sched_barrier(0);
        cur ^= 1;
    }

    const int rq = lane >> 4;
    const int wh = j0 ? wh0 : wh1;
    const int ab = j0 ? ab0 : 0;
    const int md = j0 ? mode0 : 0;
    void* Cv = j0 ? C0 : C1;
    size_t cbase = 0;
    const float* bias = b00;
    if (md == 1) {
        int chunk = n0 >> 11;
        bias = (chunk == 0) ? b00 : ((chunk == 1) ? b01 : b02);
        cbase = (size_t)chunk * ((size_t)L_TOT * DIM_C);
    }
#pragma unroll
    for (int m = 0; m < 4; ++m) {
        int row = m0 + wr * 64 + m * 16 + rq * 4;
#pragma unroll
        for (int n = 0; n < 4; ++n) {
            int col = n0 + wc * 64 + n * 16 + rl;
            int ccol = (md == 1) ? (col & 2047) : col;
            float badd = ab ? bias[ccol] : 0.0f;
#pragma unroll
            for (int j = 0; j < 4; ++j) {
                float v = acc[m][n][j] + badd;
                size_t idx = cbase + (size_t)(row + j) * ldc + ccol;
                if (wh) ((f16*)Cv)[idx] = (f16)v;
                else    ((float*)Cv)[idx] = v;
            }
        }
    }
}

// ---------------------------------------------------------------- fused RMS norm + RoPE + V-transpose (unchanged)
__global__ __launch_bounds__(256)
void norm_rope_v(const f16* __restrict__ q16, const f16* __restrict__ k16, const f16* __restrict__ v16,
                 const float* __restrict__ qs, const float* __restrict__ ks, const float* __restrict__ vs,
                 const float* __restrict__ nrope, const float* __restrict__ crope,
                 f16* __restrict__ qH, f16* __restrict__ kH, f16* __restrict__ vT) {
    __shared__ f16 vtile[128][33];
    const int t = threadIdx.x, rloc = t >> 3, c = t & 7;
    const int r = blockIdx.x * 32 + rloc, h = blockIdx.y;
    const int d0 = c * 8;
    const size_t src = (size_t)r * DIM_C + h * HD;
    half8 qlv = *(const half8*)(q16 + src + d0);
    half8 qhv = *(const half8*)(q16 + src + 64 + d0);
    half8 klv = *(const half8*)(k16 + src + d0);
    half8 khv = *(const half8*)(k16 + src + 64 + d0);
    half8 vlv = *(const half8*)(v16 + src + d0);
    half8 vhv = *(const half8*)(v16 + src + 64 + d0);
    float ql[8], qh[8], kl[8], kh[8], vl[8], vh[8];
    float sq = 0.f, sk = 0.f, sv = 0.f;
#pragma unroll
    for (int i = 0; i < 8; ++i) {
        ql[i] = (float)qlv[i]; qh[i] = (float)qhv[i];
        kl[i] = (float)klv[i]; kh[i] = (float)khv[i];
        vl[i] = (float)vlv[i]; vh[i] = (float)vhv[i];
        sq += ql[i]*ql[i] + qh[i]*qh[i];
        sk += kl[i]*kl[i] + kh[i]*kh[i];
        sv += vl[i]*vl[i] + vh[i]*vh[i];
    }
    sq += __shfl_xor(sq, 1); sq += __shfl_xor(sq, 2); sq += __shfl_xor(sq, 4);
    sk += __shfl_xor(sk, 1); sk += __shfl_xor(sk, 2); sk += __shfl_xor(sk, 4);
    sv += __shfl_xor(sv, 1); sv += __shfl_xor(sv, 2); sv += __shfl_xor(sv, 4);
    const float rqs = rsqrtf(sq * (1.0f / 128.0f) + 1e-6f);
    const float rks = rsqrtf(sk * (1.0f / 128.0f) + 1e-6f);
    const float rvs = rsqrtf(sv * (1.0f / 128.0f) + 1e-6f);
    const float* rp = (r < L_NZ) ? (nrope + (size_t)r * HD) : (crope + (size_t)(r - L_NZ) * HD);
    half8 qo_l, qo_h, ko_l, ko_h;
#pragma unroll
    for (int i = 0; i < 8; ++i) {
        float fr = rp[d0 + i];
        float cs = cosf(fr), sn = sinf(fr);
        float qnl = ql[i] * rqs * qs[d0 + i],      qnh = qh[i] * rqs * qs[64 + d0 + i];
        float knl = kl[i] * rks * ks[d0 + i],      knh = kh[i] * rks * ks[64 + d0 + i];
        qo_l[i] = (f16)((qnl * cs - qnh * sn) * 0.08838834764831845f);
        qo_h[i] = (f16)((qnh * cs + qnl * sn) * 0.08838834764831845f);
        ko_l[i] = (f16)(knl * cs - knh * sn);
        ko_h[i] = (f16)(knh * cs + knl * sn);
        vtile[d0 + i][rloc]      = (f16)(vl[i] * rvs * vs[d0 + i]);
        vtile[64 + d0 + i][rloc] = (f16)(vh[i] * rvs * vs[64 + d0 + i]);
    }
    const size_t dst = ((size_t)h * L_TOT + r) * HD;
    *(half8*)(qH + dst + d0) = qo_l;      *(half8*)(qH + dst + 64 + d0) = qo_h;
    *(half8*)(kH + dst + d0) = ko_l;      *(half8*)(kH + dst + 64 + d0) = ko_h;
    __syncthreads();
    const int dd = t >> 1, seg = (t & 1) * 16;
    half8 o0, o1;
#pragma unroll
    for (int i = 0; i < 8; ++i) { o0[i] = vtile[dd][seg + i]; o1[i] = vtile[dd][seg + 8 + i]; }
    f16* vdst = vT + ((size_t)h * HD + dd) * L_TOT + blockIdx.x * 32 + seg;
    *(half8*)(vdst)     = o0;
    *(half8*)(vdst + 8) = o1;
}

// ---------------------------------------------------------------- flash attention v6: K-sliced, 896 uniform blocks
// QBLK=128 (8 waves x 16 q, 512 thr), KVBLK=32, LDS 34.3KB -> 4 blocks/CU (all 896 resident).
// Decode: xcd=bid&7 owns heads {xcd,xcd+8}; per head 56 jobs: 48 = noise qb(16) x slice(3)
// [1024 keys each], 8 = cond qb [keys 2048-3072]. Every job = exactly 32 iterations.
// Static-max softmax (p=exp(s-4), Cauchy-Schwarz bound |s|<=11.32); l via ones-MFMA (f32).
// Noise jobs write l-normalized partial O (f16) + l (f32); combine_noise merges exactly
// (sum l_i O_i / sum l_i). Cond jobs write xH directly.
__global__ __launch_bounds__(512, 8)
void flash_kernel(const f16* __restrict__ qH, const f16* __restrict__ kH,
                  const f16* __restrict__ vT, f16* __restrict__ xH,
                  f16* __restrict__ Opart, float* __restrict__ lpart) {
    __shared__ __align__(16) f16 lds_k[2][32 * 128];
    __shared__ __align__(16) f16 lds_v[64 * 64];          // 64 d-pairs x (2d x 32k)
    __shared__ __align__(16) f16 p_lds[8][16][40];
    const int tid = threadIdx.x;
    const int lane = tid & 63, w = tid >> 6;
    const int bid = blockIdx.x;
    const int xcd = bid & 7, rr = bid >> 3;               // rr in [0,112)
    const int h = xcd + 8 * (rr / 56);
    const int s = rr % 56;
    const bool isNoise = (s < 48);
    const int qb  = isNoise ? (s / 3) : (16 + (s - 48));
    const int sl  = isNoise ? (s % 3) : 0;
    const int kLo = isNoise ? sl * 1024 : L_NZ;
    const int kHi = kLo + 1024;
    const int q0 = qb * 128 + w * 16;
    const int rl = lane & 15, rq = lane >> 4;

    half8 aq[4];
    const f16* qbase = qH + ((size_t)h * L_TOT + q0) * HD;
#pragma unroll
    for (int kc = 0; kc < 4; ++kc)
        aq[kc] = *(const half8*)(qbase + (size_t)rl * HD + kc * 32 + rq * 8);

    floatx4 acc[8] = {};
    floatx4 accl = {};
    const half8 vone = {(f16)1.f, (f16)1.f, (f16)1.f, (f16)1.f,
                        (f16)1.f, (f16)1.f, (f16)1.f, (f16)1.f};

    const f16* khead = kH + (size_t)h * L_TOT * HD;
    const f16* vhead = vT + (size_t)h * HD * L_TOT;

    // K tile 32x128 (8KB = 1 issue of 512 lanes x 16B), chunk swizzle c^(r&15)
    auto stageK = [&](int kb, int pb) {
        int r = tid >> 4, c = tid & 15;
        gl_lds16(khead + (size_t)(kb + r) * HD + ((c ^ (r & 15)) * 8),
                 &lds_k[pb][0] + tid * 8);
    };
    // V tile: pair=tid>>3 (d 2p,2p+1), c3=tid&7; g3 = c3^(pair&7); d=pair*2+(g3>>2); kchunk=g3&3
    auto stageV = [&](int kb) {
        int pair = tid >> 3, c3 = tid & 7;
        int g3 = c3 ^ (pair & 7);
        int d = pair * 2 + (g3 >> 2), kchunk = g3 & 3;
        gl_lds16(vhead + (size_t)d * L_TOT + kb + kchunk * 8,
                 lds_v + tid * 8);
    };

    asm volatile("s_waitcnt vmcnt(0)" ::: "memory");   // drain Q loads -> deterministic counts
    stageK(kLo, 0);                                     // 1 in flight
    int p = 0;
    for (int kb = kLo; kb < kHi; kb += 32) {
        const int kbn = (kb + 32 < kHi) ? (kb + 32) : kLo;
        stageV(kb);                                     // +1 (2)
        stageK(kbn, p ^ 1);                             // +1 (3)
        asm volatile("s_waitcnt vmcnt(2)" ::: "memory");       // own K(kb) landed
        __builtin_amdgcn_s_barrier();
        __builtin_amdgcn_sched_barrier(0);

        const f16* kbase = &lds_k[p][0];
        floatx4 sacc[2] = {};
        __builtin_amdgcn_s_setprio(1);
#pragma unroll
        for (int kf = 0; kf < 2; ++kf) {
            int r = kf * 16 + rl;
#pragma unroll
            for (int kc = 0; kc < 4; ++kc) {
                half8 bk = *(const half8*)(kbase + r * 128 + (((kc * 4 + rq) ^ (r & 15)) * 8));
                sacc[kf] = __builtin_amdgcn_mfma_f32_16x16x32_f16(aq[kc], bk, sacc[kf], 0, 0, 0);
            }
        }
        __builtin_amdgcn_s_setprio(0);
#pragma unroll
        for (int kf = 0; kf < 2; ++kf)
#pragma unroll
            for (int j = 0; j < 4; ++j) {
                float pv = __expf(sacc[kf][j] - 4.0f);
                p_lds[w][rq * 4 + j][kf * 16 + rl] = (f16)pv;
            }

        asm volatile("s_waitcnt vmcnt(1)" ::: "memory");       // own V(kb) landed
        __builtin_amdgcn_s_barrier();
        __builtin_amdgcn_sched_barrier(0);

        half8 ap = *(const half8*)(&p_lds[w][rl][rq * 8]);
        __builtin_amdgcn_s_setprio(1);
        accl = __builtin_amdgcn_mfma_f32_16x16x32_f16(ap, vone, accl, 0, 0, 0);
#pragma unroll
        for (int dt = 0; dt < 8; ++dt) {
            int d = dt * 16 + rl;
            int pair = d >> 1;
            int g3 = (d & 1) * 4 + rq;
            half8 bv = *(const half8*)(lds_v + pair * 64 + ((g3 ^ (pair & 7)) * 8));
            acc[dt] = __builtin_amdgcn_mfma_f32_16x16x32_f16(ap, bv, acc[dt], 0, 0, 0);
        }
        __builtin_amdgcn_s_setprio(0);
        __builtin_amdgcn_s_barrier();
        p ^= 1;
    }

    // epilogue
    if (isNoise) {
        f16* op = Opart + ((size_t)sl * NH + h) * ((size_t)L_NZ * HD);
        float* lp = lpart + ((size_t)sl * NH + h) * L_NZ;
#pragma unroll
        for (int j = 0; j < 4; ++j) {
            float li = 1.0f / accl[j];
            int row = q0 + rq * 4 + j;
            if (rl == 0) lp[row] = accl[j];
#pragma unroll
            for (int dt = 0; dt < 8; ++dt)
                op[(size_t)row * HD + dt * 16 + rl] = (f16)(acc[dt][j] * li);
        }
    } else {
#pragma unroll
        for (int j = 0; j < 4; ++j) {
            float li = 1.0f / accl[j];
            int row = q0 + rq * 4 + j;
#pragma unroll
            for (int dt = 0; dt < 8; ++dt)
                xH[(size_t)row * DIM_C + h * HD + dt * 16 + rl] = (f16)(acc[dt][j] * li);
        }
    }
}

// ---------------------------------------------------------------- combine noise partials: x = sum l_i O_i / sum l_i
__global__ __launch_bounds__(256)
void combine_noise(const f16* __restrict__ Opart, const float* __restrict__ lpart,
                   f16* __restrict__ xH) {
    const size_t PS = (size_t)NH * L_NZ * HD;   // per-slice O stride
    const int t = threadIdx.x, lr = t >> 4, dc = t & 15;
    const int R = blockIdx.x * 16 + lr;         // 0..32767 = h*2048+q
    const int h = R >> 11, q = R & 2047;
    const float l0 = lpart[(size_t)0 * NH * L_NZ + (size_t)h * L_NZ + q];
    const float l1 = lpart[(size_t)1 * NH * L_NZ + (size_t)h * L_NZ + q];
    const float l2 = lpart[(size_t)2 * NH * L_NZ + (size_t)h * L_NZ + q];
    const float inv = 1.0f / (l0 + l1 + l2);
    const size_t base = ((size_t)h * L_NZ + q) * HD + dc * 8;
    half8 a = *(const half8*)(Opart + 0 * PS + base);
    half8 b = *(const half8*)(Opart + 1 * PS + base);
    half8 c = *(const half8*)(Opart + 2 * PS + base);
    half8 out;
#pragma unroll
    for (int i = 0; i < 8; ++i)
        out[i] = (f16)((l0 * (float)a[i] + l1 * (float)b[i] + l2 * (float)c[i]) * inv);
    *(half8*)(xH + (size_t)q * DIM_C + h * HD + dc * 8) = out;
}

// ---------------------------------------------------------------- launch
extern "C" void kernel_launch(void* const* d_in, const int* in_sizes, int n_in,
                              void* d_out, int out_size, void* d_ws, size_t ws_size,
                              hipStream_t stream) {
    const float* noise = (const float*)d_in[0];
    const float* cond  = (const float*)d_in[1];
    const float* nrope = (const float*)d_in[2];
    const float* crope = (const float*)d_in[3];
    const float* Wq = (const float*)d_in[4];
    const float* Wk = (const float*)d_in[5];
    const float* Wv = (const float*)d_in[6];
    const float* Wo = (const float*)d_in[7];
    const float* bq = (const float*)d_in[8];
    const float* bk = (const float*)d_in[9];
    const float* bv = (const float*)d_in[10];
    const float* bo = (const float*)d_in[11];
    const float* qs = (const float*)d_in[12];
    const float* ks = (const float*)d_in[13];
    const float* vs = (const float*)d_in[14];
    const float* lqd = (const float*)d_in[15];
    const float* lqu = (const float*)d_in[16];
    const float* lkd = (const float*)d_in[17];
    const float* lku = (const float*)d_in[18];
    const float* lvd = (const float*)d_in[19];
    const float* lvu = (const float*)d_in[20];
    const float* lod = (const float*)d_in[21];
    const float* lou = (const float*)d_in[22];
    (void)in_sizes; (void)n_in; (void)out_size;

    char* ws = (char*)d_ws;
    const size_t SZ_LD = (size_t)L_TOT * DIM_C * sizeof(f16);
    const size_t SZ_W  = (size_t)DIM_C * DIM_C * sizeof(f16);
    size_t o = 0;
    auto take = [&](size_t b) { size_t r = o; o += (b + 255) & ~(size_t)255; return r; };
    f16* jointH = (f16*)(ws + take(SZ_LD));
    f16* WTqkv  = (f16*)(ws + take(4 * SZ_W));                  // Wq,Wk,Wv,Wo contiguous
    f16* WT3    = WTqkv + (size_t)3 * 2048 * 2048;
    f16* downT  = (f16*)(ws + take((size_t)4 * 128 * 2048 * 2));// lqd,lkd,lvd,lod
    f16* downTo = downT + (size_t)3 * 128 * 2048;
    f16* upT    = (f16*)(ws + take((size_t)4 * 2048 * 128 * 2));// lqu,lku,lvu,lou
    f16* upTo   = upT + (size_t)3 * 2048 * 128;
    f16* q16    = (f16*)(ws + take(3 * SZ_LD));                 // q,k,v contiguous
    f16* k16    = q16 + (size_t)L_TOT * DIM_C;
    f16* v16    = k16 + (size_t)L_TOT * DIM_C;
    f16* t_all  = (f16*)(ws + take((size_t)1024 * 384 * 2));
    f16* t_o    = (f16*)(ws + take((size_t)1024 * 128 * 2));
    f16* qHd    = (f16*)(ws + take(SZ_LD));
    f16* kHd    = (f16*)(ws + take(SZ_LD));
    f16* vTd    = (f16*)(ws + take(SZ_LD));
    f16* xH     = (f16*)(ws + take(SZ_LD));
    // flash partials ALIAS the q16/k16/v16 region (dead after norm_rope_v):
    // Opart 3*16*2048*128 f16 = 25.17MB, lpart 3*16*2048 f32 = 0.39MB  (region = 37.75MB)
    f16*   Opart = q16;
    float* lpart = (float*)(q16 + (size_t)3 * NH * L_NZ * HD);
    if (o > ws_size) {
        sentinel_kernel<<<1, 1, 0, stream>>>((float*)d_out);
        return;
    }

    // 1) fused cast + batched weight transposes
    cast_joint<<<dim3(6144), 256, 0, stream>>>(noise, cond, jointH);
    transpose_cast4<<<dim3(64, 64, 4), 256, 0, stream>>>(Wq, Wk, Wv, Wo, WTqkv, 2048, 2048,
                                                         (long long)2048 * 2048);
    transpose_cast4<<<dim3(4, 64, 4), 256, 0, stream>>>(lqd, lkd, lvd, lod, downT, 2048, 128,
                                                        (long long)128 * 2048);
    transpose_cast4<<<dim3(64, 4, 4), 256, 0, stream>>>(lqu, lku, lvu, lou, upT, 128, 2048,
                                                        (long long)2048 * 128);

    // 2) merged {QKV projection + lora-down} one dispatch; merged lora-up
    gemm_pair<<<dim3(1152 + 24), 256, 0, stream>>>(
        1152, 48, jointH, WTqkv, q16, bq, bk, bv, 2048, 2048, 2048, /*wh*/1, /*ab*/1, /*mode*/1,
        3, jointH + (size_t)2048 * 2048, downT, t_all, 2048, 2048, 384, /*wh*/1,
        2048);
    gemm_tn<1, 1, 0, 2><<<dim3(48, 8), 256, 0, stream>>>(t_all, upT, q16 + (size_t)2048 * 2048,
                                                         nullptr, 1024, 6144, 128, 384, 128, 2048);

    // 3) fused RMS norm + RoPE + V transpose
    norm_rope_v<<<dim3(96, 16), 256, 0, stream>>>(q16, k16, v16, qs, ks, vs, nrope, crope,
                                                  qHd, kHd, vTd);

    // 4) flash attention (K-sliced) -> partials + xH cond; combine noise
    flash_kernel<<<dim3(896), 512, 0, stream>>>(qHd, kHd, vTd, xH, Opart, lpart);
    combine_noise<<<dim3(2048), 256, 0, stream>>>(Opart, lpart, xH);

    // 5) merged {output projection + lora-o-down}; lora-o-up accumulates into f32 out
    gemm_pair<<<dim3(384 + 8), 256, 0, stream>>>(
        384, 16, xH, WT3, d_out, bo, nullptr, nullptr, 2048, 2048, 2048, /*wh*/0, /*ab*/1, /*mode*/0,
        1, xH + (size_t)2048 * 2048, downTo, t_o, 2048, 2048, 128, /*wh*/1,
        2048);
    gemm_tn<0, 1, 0, 0><<<dim3(16, 8), 256, 0, stream>>>(t_o, upTo, (float*)d_out + (size_t)2048 * 2048,
                                                         nullptr, 1024, 2048, 128, 128, 128, 2048);
}

// Round 13
// 325.814 us; speedup vs baseline: 1.8683x; 1.8683x over previous
//
#include <hip/hip_runtime.h>

typedef _Float16 f16;
typedef _Float16 half8 __attribute__((ext_vector_type(8)));
typedef float floatx4 __attribute__((ext_vector_type(4)));

#define L_TOT   3072
#define L_NZ    2048
#define DIM_C   2048
#define NH      16
#define HD      128

// ---------------------------------------------------------------- helpers
__device__ __forceinline__ void gl_lds16(const f16* g, f16* l) {
    __builtin_amdgcn_global_load_lds((__attribute__((address_space(1))) void*)g,
                                     (__attribute__((address_space(3))) void*)l,
                                     16, 0, 0);
}

__global__ void sentinel_kernel(float* out) { out[0] = 1.0e6f; }

// ---------------------------------------------------------------- fused cast: joint = [noise;cond] f32 -> f16
__global__ __launch_bounds__(256)
void cast_joint(const float* __restrict__ noise, const float* __restrict__ cond,
                f16* __restrict__ out) {
    int i = (blockIdx.x * 256 + threadIdx.x) * 4;
    const float* src; int off;
    if (i < 2048 * 2048) { src = noise; off = i; }
    else                 { src = cond;  off = i - 2048 * 2048; }
    float4 v = *(const float4*)(src + off);
    out[i+0] = (f16)v.x; out[i+1] = (f16)v.y;
    out[i+2] = (f16)v.z; out[i+3] = (f16)v.w;
}

// ---------------------------------------------------------------- batched transpose(+cast): out[z][c][r] = in_z[r][c]
__global__ __launch_bounds__(256)
void transpose_cast4(const float* __restrict__ s0, const float* __restrict__ s1,
                     const float* __restrict__ s2, const float* __restrict__ s3,
                     f16* __restrict__ dstBase, int R, int C, long long outBatch) {
    const float* in = (blockIdx.z == 0) ? s0 : (blockIdx.z == 1) ? s1 : (blockIdx.z == 2) ? s2 : s3;
    f16* out = dstBase + (long long)blockIdx.z * outBatch;
    __shared__ f16 tile[32][33];
    int x = threadIdx.x & 31, y0 = threadIdx.x >> 5;
    int r0 = blockIdx.y * 32, c0 = blockIdx.x * 32;
#pragma unroll
    for (int i = 0; i < 4; ++i) {
        int y = y0 + i * 8;
        tile[y][x] = (f16)in[(size_t)(r0 + y) * C + (c0 + x)];
    }
    __syncthreads();
#pragma unroll
    for (int i = 0; i < 4; ++i) {
        int y = y0 + i * 8;
        out[(size_t)(c0 + y) * R + (r0 + x)] = tile[x][y];
    }
}

// ---------------------------------------------------------------- GEMM v2 (template): C = A * BT^T
// 128x128 tile, BK=64, XOR-swizzled LDS, double-buffered counted vmcnt(8).
// MODE 0: plain. MODE 2: lora-up merged (A += chunk*128, per-chunk C base).
template<int WRITE_HALF, int ACCUM, int ADD_BIAS, int MODE>
__global__ __launch_bounds__(256, 2)
void gemm_tn(const f16* __restrict__ A, const f16* __restrict__ BT,
             void* __restrict__ Cv,
             const float* __restrict__ bias0,
             int M, int N, int K, int lda, int ldb, int ldc) {
    __shared__ __align__(16) f16 lds[2][2][128 * 64];
    const int tid  = threadIdx.x;
    const int lane = tid & 63, wave = tid >> 6;
    const int m0 = blockIdx.y * 128, n0 = blockIdx.x * 128;
    const int wr = wave >> 1, wc = wave & 1;
    floatx4 acc[4][4] = {};

    if (MODE == 2) A += (size_t)(n0 >> 11) * 128;

    const int r0i = tid >> 3;
    const int gch = (tid & 7) ^ (r0i & 7);
    const f16* gA0 = A  + (size_t)(m0 + r0i) * lda + gch * 8;
    const f16* gB0 = BT + (size_t)(n0 + r0i) * ldb + gch * 8;
    const int ldsW = wave * 512;

    auto stage = [&](int buf, int k0) {
#pragma unroll
        for (int is = 0; is < 4; ++is)
            gl_lds16(gA0 + k0 + (size_t)is * 32 * lda, &lds[buf][0][0] + is * 2048 + ldsW);
#pragma unroll
        for (int is = 0; is < 4; ++is)
            gl_lds16(gB0 + k0 + (size_t)is * 32 * ldb, &lds[buf][1][0] + is * 2048 + ldsW);
    };

    const int rl = lane & 15, cq = lane >> 4;

    const int nIter = K >> 6;
    stage(0, 0);
    int cur = 0;
    for (int t = 0; t < nIter; ++t) {
        const int k0n = (t + 1 < nIter) ? (t + 1) * 64 : 0;
        stage(cur ^ 1, k0n);
        asm volatile("s_waitcnt vmcnt(8)" ::: "memory");
        __builtin_amdgcn_s_barrier();
        __builtin_amdgcn_sched_barrier(0);
#pragma unroll
        for (int kh = 0; kh < 2; ++kh) {
            half8 af[4], bf[4];
#pragma unroll
            for (int m = 0; m < 4; ++m) {
                int row = wr * 64 + m * 16 + rl;
                int pos = (kh * 4 + cq) ^ (row & 7);
                af[m] = *(const half8*)(&lds[cur][0][row * 64 + pos * 8]);
            }
#pragma unroll
            for (int n = 0; n < 4; ++n) {
                int row = wc * 64 + n * 16 + rl;
                int pos = (kh * 4 + cq) ^ (row & 7);
                bf[n] = *(const half8*)(&lds[cur][1][row * 64 + pos * 8]);
            }
#pragma unroll
            for (int m = 0; m < 4; ++m)
#pragma unroll
                for (int n = 0; n < 4; ++n)
                    acc[m][n] = __builtin_amdgcn_mfma_f32_16x16x32_f16(af[m], bf[n], acc[m][n], 0, 0, 0);
        }
        __builtin_amdgcn_s_barrier();
        __builtin_amdgcn_sched_barrier(0);
        cur ^= 1;
    }

    const int rq = lane >> 4;
    size_t cbase = 0;
    if (MODE == 2) cbase = (size_t)(n0 >> 11) * ((size_t)L_TOT * DIM_C);
#pragma unroll
    for (int m = 0; m < 4; ++m) {
        int row = m0 + wr * 64 + m * 16 + rq * 4;
#pragma unroll
        for (int n = 0; n < 4; ++n) {
            int col = n0 + wc * 64 + n * 16 + rl;
            int ccol = (MODE == 2) ? (col & 2047) : col;
            float badd = ADD_BIAS ? bias0[ccol] : 0.0f;
#pragma unroll
            for (int j = 0; j < 4; ++j) {
                float v = acc[m][n][j] + badd;
                size_t idx = cbase + (size_t)(row + j) * ldc + ccol;
                if (WRITE_HALF) {
                    f16* C = (f16*)Cv;
                    if (ACCUM) v += (float)C[idx];
                    C[idx] = (f16)v;
                } else {
                    float* C = (float*)Cv;
                    if (ACCUM) v += C[idx];
                    C[idx] = v;
                }
            }
        }
    }
}

// ---------------------------------------------------------------- dual-job GEMM (runtime params; hot loop identical)
__global__ __launch_bounds__(256, 2)
void gemm_pair(int nb0, int nbx0,
               const f16* __restrict__ A0, const f16* __restrict__ BT0, void* C0,
               const float* __restrict__ b00, const float* __restrict__ b01, const float* __restrict__ b02,
               int lda0, int ldb0, int ldc0, int wh0, int ab0, int mode0,
               int nbx1,
               const f16* __restrict__ A1, const f16* __restrict__ BT1, void* C1,
               int lda1, int ldb1, int ldc1, int wh1,
               int K) {
    __shared__ __align__(16) f16 lds[2][2][128 * 64];
    const int tid  = threadIdx.x;
    const int lane = tid & 63, wave = tid >> 6;
    const int bid = blockIdx.x;
    const bool j0 = (bid < nb0);
    const int lb  = j0 ? bid : (bid - nb0);
    const int nbx = j0 ? nbx0 : nbx1;
    const int bx = lb % nbx, by = lb / nbx;
    const int m0 = by * 128, n0 = bx * 128;
    const f16* A  = j0 ? A0  : A1;
    const f16* BT = j0 ? BT0 : BT1;
    const int lda = j0 ? lda0 : lda1, ldb = j0 ? ldb0 : ldb1, ldc = j0 ? ldc0 : ldc1;
    const int wr = wave >> 1, wc = wave & 1;
    floatx4 acc[4][4] = {};

    const int r0i = tid >> 3;
    const int gch = (tid & 7) ^ (r0i & 7);
    const f16* gA0 = A  + (size_t)(m0 + r0i) * lda + gch * 8;
    const f16* gB0 = BT + (size_t)(n0 + r0i) * ldb + gch * 8;
    const int ldsW = wave * 512;

    auto stage = [&](int buf, int k0) {
#pragma unroll
        for (int is = 0; is < 4; ++is)
            gl_lds16(gA0 + k0 + (size_t)is * 32 * lda, &lds[buf][0][0] + is * 2048 + ldsW);
#pragma unroll
        for (int is = 0; is < 4; ++is)
            gl_lds16(gB0 + k0 + (size_t)is * 32 * ldb, &lds[buf][1][0] + is * 2048 + ldsW);
    };

    const int rl = lane & 15, cq = lane >> 4;
    const int nIter = K >> 6;
    stage(0, 0);
    int cur = 0;
    for (int t = 0; t < nIter; ++t) {
        const int k0n = (t + 1 < nIter) ? (t + 1) * 64 : 0;
        stage(cur ^ 1, k0n);
        asm volatile("s_waitcnt vmcnt(8)" ::: "memory");
        __builtin_amdgcn_s_barrier();
        __builtin_amdgcn_sched_barrier(0);
#pragma unroll
        for (int kh = 0; kh < 2; ++kh) {
            half8 af[4], bf[4];
#pragma unroll
            for (int m = 0; m < 4; ++m) {
                int row = wr * 64 + m * 16 + rl;
                int pos = (kh * 4 + cq) ^ (row & 7);
                af[m] = *(const half8*)(&lds[cur][0][row * 64 + pos * 8]);
            }
#pragma unroll
            for (int n = 0; n < 4; ++n) {
                int row = wc * 64 + n * 16 + rl;
                int pos = (kh * 4 + cq) ^ (row & 7);
                bf[n] = *(const half8*)(&lds[cur][1][row * 64 + pos * 8]);
            }
#pragma unroll
            for (int m = 0; m < 4; ++m)
#pragma unroll
                for (int n = 0; n < 4; ++n)
                    acc[m][n] = __builtin_amdgcn_mfma_f32_16x16x32_f16(af[m], bf[n], acc[m][n], 0, 0, 0);
        }
        __builtin_amdgcn_s_barrier();
        __builtin_amdgcn_sched_barrier(0);
        cur ^= 1;
    }

    const int rq = lane >> 4;
    const int wh = j0 ? wh0 : wh1;
    const int ab = j0 ? ab0 : 0;
    const int md = j0 ? mode0 : 0;
    void* Cv = j0 ? C0 : C1;
    size_t cbase = 0;
    const float* bias = b00;
    if (md == 1) {
        int chunk = n0 >> 11;
        bias = (chunk == 0) ? b00 : ((chunk == 1) ? b01 : b02);
        cbase = (size_t)chunk * ((size_t)L_TOT * DIM_C);
    }
#pragma unroll
    for (int m = 0; m < 4; ++m) {
        int row = m0 + wr * 64 + m * 16 + rq * 4;
#pragma unroll
        for (int n = 0; n < 4; ++n) {
            int col = n0 + wc * 64 + n * 16 + rl;
            int ccol = (md == 1) ? (col & 2047) : col;
            float badd = ab ? bias[ccol] : 0.0f;
#pragma unroll
            for (int j = 0; j < 4; ++j) {
                float v = acc[m][n][j] + badd;
                size_t idx = cbase + (size_t)(row + j) * ldc + ccol;
                if (wh) ((f16*)Cv)[idx] = (f16)v;
                else    ((float*)Cv)[idx] = v;
            }
        }
    }
}

// ---------------------------------------------------------------- fused RMS norm + RoPE + V-transpose (unchanged)
__global__ __launch_bounds__(256)
void norm_rope_v(const f16* __restrict__ q16, const f16* __restrict__ k16, const f16* __restrict__ v16,
                 const float* __restrict__ qs, const float* __restrict__ ks, const float* __restrict__ vs,
                 const float* __restrict__ nrope, const float* __restrict__ crope,
                 f16* __restrict__ qH, f16* __restrict__ kH, f16* __restrict__ vT) {
    __shared__ f16 vtile[128][33];
    const int t = threadIdx.x, rloc = t >> 3, c = t & 7;
    const int r = blockIdx.x * 32 + rloc, h = blockIdx.y;
    const int d0 = c * 8;
    const size_t src = (size_t)r * DIM_C + h * HD;
    half8 qlv = *(const half8*)(q16 + src + d0);
    half8 qhv = *(const half8*)(q16 + src + 64 + d0);
    half8 klv = *(const half8*)(k16 + src + d0);
    half8 khv = *(const half8*)(k16 + src + 64 + d0);
    half8 vlv = *(const half8*)(v16 + src + d0);
    half8 vhv = *(const half8*)(v16 + src + 64 + d0);
    float ql[8], qh[8], kl[8], kh[8], vl[8], vh[8];
    float sq = 0.f, sk = 0.f, sv = 0.f;
#pragma unroll
    for (int i = 0; i < 8; ++i) {
        ql[i] = (float)qlv[i]; qh[i] = (float)qhv[i];
        kl[i] = (float)klv[i]; kh[i] = (float)khv[i];
        vl[i] = (float)vlv[i]; vh[i] = (float)vhv[i];
        sq += ql[i]*ql[i] + qh[i]*qh[i];
        sk += kl[i]*kl[i] + kh[i]*kh[i];
        sv += vl[i]*vl[i] + vh[i]*vh[i];
    }
    sq += __shfl_xor(sq, 1); sq += __shfl_xor(sq, 2); sq += __shfl_xor(sq, 4);
    sk += __shfl_xor(sk, 1); sk += __shfl_xor(sk, 2); sk += __shfl_xor(sk, 4);
    sv += __shfl_xor(sv, 1); sv += __shfl_xor(sv, 2); sv += __shfl_xor(sv, 4);
    const float rqs = rsqrtf(sq * (1.0f / 128.0f) + 1e-6f);
    const float rks = rsqrtf(sk * (1.0f / 128.0f) + 1e-6f);
    const float rvs = rsqrtf(sv * (1.0f / 128.0f) + 1e-6f);
    const float* rp = (r < L_NZ) ? (nrope + (size_t)r * HD) : (crope + (size_t)(r - L_NZ) * HD);
    half8 qo_l, qo_h, ko_l, ko_h;
#pragma unroll
    for (int i = 0; i < 8; ++i) {
        float fr = rp[d0 + i];
        float cs = cosf(fr), sn = sinf(fr);
        float qnl = ql[i] * rqs * qs[d0 + i],      qnh = qh[i] * rqs * qs[64 + d0 + i];
        float knl = kl[i] * rks * ks[d0 + i],      knh = kh[i] * rks * ks[64 + d0 + i];
        qo_l[i] = (f16)((qnl * cs - qnh * sn) * 0.08838834764831845f);
        qo_h[i] = (f16)((qnh * cs + qnl * sn) * 0.08838834764831845f);
        ko_l[i] = (f16)(knl * cs - knh * sn);
        ko_h[i] = (f16)(knh * cs + knl * sn);
        vtile[d0 + i][rloc]      = (f16)(vl[i] * rvs * vs[d0 + i]);
        vtile[64 + d0 + i][rloc] = (f16)(vh[i] * rvs * vs[64 + d0 + i]);
    }
    const size_t dst = ((size_t)h * L_TOT + r) * HD;
    *(half8*)(qH + dst + d0) = qo_l;      *(half8*)(qH + dst + 64 + d0) = qo_h;
    *(half8*)(kH + dst + d0) = ko_l;      *(half8*)(kH + dst + 64 + d0) = ko_h;
    __syncthreads();
    const int dd = t >> 1, seg = (t & 1) * 16;
    half8 o0, o1;
#pragma unroll
    for (int i = 0; i < 8; ++i) { o0[i] = vtile[dd][seg + i]; o1[i] = vtile[dd][seg + 8 + i]; }
    f16* vdst = vT + ((size_t)h * HD + dd) * L_TOT + blockIdx.x * 32 + seg;
    *(half8*)(vdst)     = o0;
    *(half8*)(vdst + 8) = o1;
}

// ---------------------------------------------------------------- flash attention v6b: K-sliced, 896 uniform blocks
// IDENTICAL to v6 except __launch_bounds__(512, 4): Round-12's (512,8) capped VGPR at 64
// -> full spill -> 900MB scratch traffic. At 4 waves/EU the cap is 128 VGPR (kernel needs
// ~90): no spill, 2 blocks/CU x 8 waves = 16 waves/CU (2x the v4 structure).
__global__ __launch_bounds__(512, 4)
void flash_kernel(const f16* __restrict__ qH, const f16* __restrict__ kH,
                  const f16* __restrict__ vT, f16* __restrict__ xH,
                  f16* __restrict__ Opart, float* __restrict__ lpart) {
    __shared__ __align__(16) f16 lds_k[2][32 * 128];
    __shared__ __align__(16) f16 lds_v[64 * 64];          // 64 d-pairs x (2d x 32k)
    __shared__ __align__(16) f16 p_lds[8][16][40];
    const int tid = threadIdx.x;
    const int lane = tid & 63, w = tid >> 6;
    const int bid = blockIdx.x;
    const int xcd = bid & 7, rr = bid >> 3;               // rr in [0,112)
    const int h = xcd + 8 * (rr / 56);
    const int s = rr % 56;
    const bool isNoise = (s < 48);
    const int qb  = isNoise ? (s / 3) : (16 + (s - 48));
    const int sl  = isNoise ? (s % 3) : 0;
    const int kLo = isNoise ? sl * 1024 : L_NZ;
    const int kHi = kLo + 1024;
    const int q0 = qb * 128 + w * 16;
    const int rl = lane & 15, rq = lane >> 4;

    half8 aq[4];
    const f16* qbase = qH + ((size_t)h * L_TOT + q0) * HD;
#pragma unroll
    for (int kc = 0; kc < 4; ++kc)
        aq[kc] = *(const half8*)(qbase + (size_t)rl * HD + kc * 32 + rq * 8);

    floatx4 acc[8] = {};
    floatx4 accl = {};
    const half8 vone = {(f16)1.f, (f16)1.f, (f16)1.f, (f16)1.f,
                        (f16)1.f, (f16)1.f, (f16)1.f, (f16)1.f};

    const f16* khead = kH + (size_t)h * L_TOT * HD;
    const f16* vhead = vT + (size_t)h * HD * L_TOT;

    // K tile 32x128 (8KB = 1 issue of 512 lanes x 16B), chunk swizzle c^(r&15)
    auto stageK = [&](int kb, int pb) {
        int r = tid >> 4, c = tid & 15;
        gl_lds16(khead + (size_t)(kb + r) * HD + ((c ^ (r & 15)) * 8),
                 &lds_k[pb][0] + tid * 8);
    };
    // V tile: pair=tid>>3 (d 2p,2p+1), c3=tid&7; g3 = c3^(pair&7); d=pair*2+(g3>>2); kchunk=g3&3
    auto stageV = [&](int kb) {
        int pair = tid >> 3, c3 = tid & 7;
        int g3 = c3 ^ (pair & 7);
        int d = pair * 2 + (g3 >> 2), kchunk = g3 & 3;
        gl_lds16(vhead + (size_t)d * L_TOT + kb + kchunk * 8,
                 lds_v + tid * 8);
    };

    asm volatile("s_waitcnt vmcnt(0)" ::: "memory");   // drain Q loads -> deterministic counts
    stageK(kLo, 0);                                     // 1 in flight
    int p = 0;
    for (int kb = kLo; kb < kHi; kb += 32) {
        const int kbn = (kb + 32 < kHi) ? (kb + 32) : kLo;
        stageV(kb);                                     // +1 (2)
        stageK(kbn, p ^ 1);                             // +1 (3)
        asm volatile("s_waitcnt vmcnt(2)" ::: "memory");       // own K(kb) landed
        __builtin_amdgcn_s_barrier();
        __builtin_amdgcn_sched_barrier(0);

        const f16* kbase = &lds_k[p][0];
        floatx4 sacc[2] = {};
        __builtin_amdgcn_s_setprio(1);
#pragma unroll
        for (int kf = 0; kf < 2; ++kf) {
            int r = kf * 16 + rl;
#pragma unroll
            for (int kc = 0; kc < 4; ++kc) {
                half8 bk = *(const half8*)(kbase + r * 128 + (((kc * 4 + rq) ^ (r & 15)) * 8));
                sacc[kf] = __builtin_amdgcn_mfma_f32_16x16x32_f16(aq[kc], bk, sacc[kf], 0, 0, 0);
            }
        }
        __builtin_amdgcn_s_setprio(0);
#pragma unroll
        for (int kf = 0; kf < 2; ++kf)
#pragma unroll
            for (int j = 0; j < 4; ++j) {
                float pv = __expf(sacc[kf][j] - 4.0f);
                p_lds[w][rq * 4 + j][kf * 16 + rl] = (f16)pv;
            }

        asm volatile("s_waitcnt vmcnt(1)" ::: "memory");       // own V(kb) landed
        __builtin_amdgcn_s_barrier();
        __builtin_amdgcn_sched_barrier(0);

        half8 ap = *(const half8*)(&p_lds[w][rl][rq * 8]);
        __builtin_amdgcn_s_setprio(1);
        accl = __builtin_amdgcn_mfma_f32_16x16x32_f16(ap, vone, accl, 0, 0, 0);
#pragma unroll
        for (int dt = 0; dt < 8; ++dt) {
            int d = dt * 16 + rl;
            int pair = d >> 1;
            int g3 = (d & 1) * 4 + rq;
            half8 bv = *(const half8*)(lds_v + pair * 64 + ((g3 ^ (pair & 7)) * 8));
            acc[dt] = __builtin_amdgcn_mfma_f32_16x16x32_f16(ap, bv, acc[dt], 0, 0, 0);
        }
        __builtin_amdgcn_s_setprio(0);
        __builtin_amdgcn_s_barrier();
        p ^= 1;
    }

    // epilogue
    if (isNoise) {
        f16* op = Opart + ((size_t)sl * NH + h) * ((size_t)L_NZ * HD);
        float* lp = lpart + ((size_t)sl * NH + h) * L_NZ;
#pragma unroll
        for (int j = 0; j < 4; ++j) {
            float li = 1.0f / accl[j];
            int row = q0 + rq * 4 + j;
            if (rl == 0) lp[row] = accl[j];
#pragma unroll
            for (int dt = 0; dt < 8; ++dt)
                op[(size_t)row * HD + dt * 16 + rl] = (f16)(acc[dt][j] * li);
        }
    } else {
#pragma unroll
        for (int j = 0; j < 4; ++j) {
            float li = 1.0f / accl[j];
            int row = q0 + rq * 4 + j;
#pragma unroll
            for (int dt = 0; dt < 8; ++dt)
                xH[(size_t)row * DIM_C + h * HD + dt * 16 + rl] = (f16)(acc[dt][j] * li);
        }
    }
}

// ---------------------------------------------------------------- combine noise partials: x = sum l_i O_i / sum l_i
__global__ __launch_bounds__(256)
void combine_noise(const f16* __restrict__ Opart, const float* __restrict__ lpart,
                   f16* __restrict__ xH) {
    const size_t PS = (size_t)NH * L_NZ * HD;   // per-slice O stride
    const int t = threadIdx.x, lr = t >> 4, dc = t & 15;
    const int R = blockIdx.x * 16 + lr;         // 0..32767 = h*2048+q
    const int h = R >> 11, q = R & 2047;
    const float l0 = lpart[(size_t)0 * NH * L_NZ + (size_t)h * L_NZ + q];
    const float l1 = lpart[(size_t)1 * NH * L_NZ + (size_t)h * L_NZ + q];
    const float l2 = lpart[(size_t)2 * NH * L_NZ + (size_t)h * L_NZ + q];
    const float inv = 1.0f / (l0 + l1 + l2);
    const size_t base = ((size_t)h * L_NZ + q) * HD + dc * 8;
    half8 a = *(const half8*)(Opart + 0 * PS + base);
    half8 b = *(const half8*)(Opart + 1 * PS + base);
    half8 c = *(const half8*)(Opart + 2 * PS + base);
    half8 out;
#pragma unroll
    for (int i = 0; i < 8; ++i)
        out[i] = (f16)((l0 * (float)a[i] + l1 * (float)b[i] + l2 * (float)c[i]) * inv);
    *(half8*)(xH + (size_t)q * DIM_C + h * HD + dc * 8) = out;
}

// ---------------------------------------------------------------- launch
extern "C" void kernel_launch(void* const* d_in, const int* in_sizes, int n_in,
                              void* d_out, int out_size, void* d_ws, size_t ws_size,
                              hipStream_t stream) {
    const float* noise = (const float*)d_in[0];
    const float* cond  = (const float*)d_in[1];
    const float* nrope = (const float*)d_in[2];
    const float* crope = (const float*)d_in[3];
    const float* Wq = (const float*)d_in[4];
    const float* Wk = (const float*)d_in[5];
    const float* Wv = (const float*)d_in[6];
    const float* Wo = (const float*)d_in[7];
    const float* bq = (const float*)d_in[8];
    const float* bk = (const float*)d_in[9];
    const float* bv = (const float*)d_in[10];
    const float* bo = (const float*)d_in[11];
    const float* qs = (const float*)d_in[12];
    const float* ks = (const float*)d_in[13];
    const float* vs = (const float*)d_in[14];
    const float* lqd = (const float*)d_in[15];
    const float* lqu = (const float*)d_in[16];
    const float* lkd = (const float*)d_in[17];
    const float* lku = (const float*)d_in[18];
    const float* lvd = (const float*)d_in[19];
    const float* lvu = (const float*)d_in[20];
    const float* lod = (const float*)d_in[21];
    const float* lou = (const float*)d_in[22];
    (void)in_sizes; (void)n_in; (void)out_size;

    char* ws = (char*)d_ws;
    const size_t SZ_LD = (size_t)L_TOT * DIM_C * sizeof(f16);
    const size_t SZ_W  = (size_t)DIM_C * DIM_C * sizeof(f16);
    size_t o = 0;
    auto take = [&](size_t b) { size_t r = o; o += (b + 255) & ~(size_t)255; return r; };
    f16* jointH = (f16*)(ws + take(SZ_LD));
    f16* WTqkv  = (f16*)(ws + take(4 * SZ_W));                  // Wq,Wk,Wv,Wo contiguous
    f16* WT3    = WTqkv + (size_t)3 * 2048 * 2048;
    f16* downT  = (f16*)(ws + take((size_t)4 * 128 * 2048 * 2));// lqd,lkd,lvd,lod
    f16* downTo = downT + (size_t)3 * 128 * 2048;
    f16* upT    = (f16*)(ws + take((size_t)4 * 2048 * 128 * 2));// lqu,lku,lvu,lou
    f16* upTo   = upT + (size_t)3 * 2048 * 128;
    f16* q16    = (f16*)(ws + take(3 * SZ_LD));                 // q,k,v contiguous
    f16* k16    = q16 + (size_t)L_TOT * DIM_C;
    f16* v16    = k16 + (size_t)L_TOT * DIM_C;
    f16* t_all  = (f16*)(ws + take((size_t)1024 * 384 * 2));
    f16* t_o    = (f16*)(ws + take((size_t)1024 * 128 * 2));
    f16* qHd    = (f16*)(ws + take(SZ_LD));
    f16* kHd    = (f16*)(ws + take(SZ_LD));
    f16* vTd    = (f16*)(ws + take(SZ_LD));
    f16* xH     = (f16*)(ws + take(SZ_LD));
    // flash partials ALIAS the q16/k16/v16 region (dead after norm_rope_v):
    // Opart 3*16*2048*128 f16 = 25.17MB, lpart 3*16*2048 f32 = 0.39MB  (region = 37.75MB)
    f16*   Opart = q16;
    float* lpart = (float*)(q16 + (size_t)3 * NH * L_NZ * HD);
    if (o > ws_size) {
        sentinel_kernel<<<1, 1, 0, stream>>>((float*)d_out);
        return;
    }

    // 1) fused cast + batched weight transposes
    cast_joint<<<dim3(6144), 256, 0, stream>>>(noise, cond, jointH);
    transpose_cast4<<<dim3(64, 64, 4), 256, 0, stream>>>(Wq, Wk, Wv, Wo, WTqkv, 2048, 2048,
                                                         (long long)2048 * 2048);
    transpose_cast4<<<dim3(4, 64, 4), 256, 0, stream>>>(lqd, lkd, lvd, lod, downT, 2048, 128,
                                                        (long long)128 * 2048);
    transpose_cast4<<<dim3(64, 4, 4), 256, 0, stream>>>(lqu, lku, lvu, lou, upT, 128, 2048,
                                                        (long long)2048 * 128);

    // 2) merged {QKV projection + lora-down} one dispatch; merged lora-up
    gemm_pair<<<dim3(1152 + 24), 256, 0, stream>>>(
        1152, 48, jointH, WTqkv, q16, bq, bk, bv, 2048, 2048, 2048, /*wh*/1, /*ab*/1, /*mode*/1,
        3, jointH + (size_t)2048 * 2048, downT, t_all, 2048, 2048, 384, /*wh*/1,
        2048);
    gemm_tn<1, 1, 0, 2><<<dim3(48, 8), 256, 0, stream>>>(t_all, upT, q16 + (size_t)2048 * 2048,
                                                         nullptr, 1024, 6144, 128, 384, 128, 2048);

    // 3) fused RMS norm + RoPE + V transpose
    norm_rope_v<<<dim3(96, 16), 256, 0, stream>>>(q16, k16, v16, qs, ks, vs, nrope, crope,
                                                  qHd, kHd, vTd);

    // 4) flash attention (K-sliced) -> partials + xH cond; combine noise
    flash_kernel<<<dim3(896), 512, 0, stream>>>(qHd, kHd, vTd, xH, Opart, lpart);
    combine_noise<<<dim3(2048), 256, 0, stream>>>(Opart, lpart, xH);

    // 5) merged {output projection + lora-o-down}; lora-o-up accumulates into f32 out
    gemm_pair<<<dim3(384 + 8), 256, 0, stream>>>(
        384, 16, xH, WT3, d_out, bo, nullptr, nullptr, 2048, 2048, 2048, /*wh*/0, /*ab*/1, /*mode*/0,
        1, xH + (size_t)2048 * 2048, downTo, t_o, 2048, 2048, 128, /*wh*/1,
        2048);
    gemm_tn<0, 1, 0, 0><<<dim3(16, 8), 256, 0, stream>>>(t_o, upTo, (float*)d_out + (size_t)2048 * 2048,
                                                         nullptr, 1024, 2048, 128, 128, 128, 2048);
}